// Round 12
// baseline (414.525 us; speedup 1.0000x reference)
//
#include <hip/hip_runtime.h>
#include <hip/hip_bf16.h>

// Problem constants
#define BB 8
#define SS 2048
#define HD 512   // H*DK
#define DM 512

typedef __attribute__((ext_vector_type(8))) short short8;   // 8 bf16
typedef __attribute__((ext_vector_type(4))) short short4v;  // 4 bf16
typedef __attribute__((ext_vector_type(4))) float floatx4;  // MFMA C/D

// HW packed f32->bf16 (RNE): gfx950 v_cvt_pk_bf16_f32, low half = a.
__device__ __forceinline__ unsigned cvt_pk_bf16(float a, float b) {
    unsigned r;
    asm("v_cvt_pk_bf16_f32 %0, %1, %2" : "=v"(r) : "v"(a), "v"(b));
    return r;
}

__device__ __forceinline__ short f2bf(float f) {
    return (short)(cvt_pk_bf16(f, f) & 0xFFFFu);
}

__device__ __forceinline__ uint2 pack4bf(float a, float b, float cc, float d) {
    return uint2{cvt_pk_bf16(a, b), cvt_pk_bf16(cc, d)};
}

__device__ __forceinline__ short4v pack4bf_s4(float a, float b, float cc, float d) {
    uint2 u = pack4bf(a, b, cc, d);
    short4v s;
    __builtin_memcpy(&s, &u, 8);
    return s;
}

// async global->LDS, 16B per lane. Dest MUST be wave-uniform base + lane*16.
__device__ __forceinline__ void async_copy16(const short* g, short* l) {
    __builtin_amdgcn_global_load_lds(
        (const __attribute__((address_space(1))) void*)g,
        (__attribute__((address_space(3))) void*)l, 16, 0, 0);
}

// ---------------------------------------------------------------------------
// Tiny dispatch 1: WqT[512][64] transpose only (needed by proj in dispatch 2).
// ---------------------------------------------------------------------------
__global__ void wqt_prep_kernel(const float* __restrict__ Wq,
                                short* __restrict__ WqT) {
    int idx = blockIdx.x * 256 + threadIdx.x;   // 0..32767
    int o = idx >> 6, i = idx & 63;
    WqT[idx] = f2bf(Wq[i * HD + o]);
}

// ---------------------------------------------------------------------------
// Dispatch 2 — fused aux: maskbits (ballot) + WoT transpose + q/k/v proj,
// all independent given WqT. Mask blocks first (flood HBM), proj trails and
// overlaps the mask tail. Proj body verbatim R9 (LDS-bounced epilogue).
//  bid [0,16384):      mask row bid (ballot: bit l <-> col g*64+l)
//  bid [16384,17408):  WoT transpose
//  bid [17408,18944):  proj (pbid = bid-17408; part = pbid>>9, sub = pbid&511)
// ---------------------------------------------------------------------------
__global__ __launch_bounds__(256, 2) void fused_aux_kernel(
    const float* __restrict__ mask, unsigned long long* __restrict__ bits,
    const float* __restrict__ Wo, short* __restrict__ WoT,
    const float* __restrict__ qA, const float* __restrict__ kA,
    const float* __restrict__ vA, const short* __restrict__ WqT,
    const float* __restrict__ bq, short* __restrict__ qh,
    short* __restrict__ khS, short* __restrict__ vI) {
    const int bid = blockIdx.x;
    __shared__ __align__(16) short LDSbuf[2 * 128 * 80];   // 40 KB (proj only)

    if (bid < 16384) {
        const int lane = threadIdx.x & 63, w = threadIdx.x >> 6;
        const float* mrow = mask + (size_t)bid * 2048;
        unsigned long long* brow = bits + (size_t)bid * 32;
#pragma unroll
        for (int i = 0; i < 8; ++i) {
            int g = w * 8 + i;                   // word 0..31 of this row
            float v = mrow[g * 64 + lane];
            unsigned long long word = __ballot(v == 1.0f);
            if (lane == 0) brow[g] = word;
        }
        return;
    }
    if (bid < 17408) {
        int idx = (bid - 16384) * 256 + threadIdx.x;     // 0..262143
        int o = idx >> 9, i = idx & 511;
        WoT[idx] = f2bf(Wo[i * DM + o]);
        return;
    }

    // ---------------- proj (verbatim R9 body) ----------------
    const int pbid = bid - 17408;        // 0..1535
    const int part = pbid >> 9, sub = pbid & 511;

    short* As = LDSbuf;
    short* Bs = LDSbuf + 128 * 80;
    short* Cs = LDSbuf;                  // 32 KB reuse after compute

    const int tid = threadIdx.x, lane = tid & 63, w = tid >> 6;
    const int c = lane & 15, Q = lane >> 4;
    const int wm = w >> 1, wn = w & 1;

    int n0, m0, bz = 0;
    const float* Af32 = nullptr;
    if (part < 2) {
        n0 = (sub & 3) * 128;
        m0 = (sub >> 2) * 128;
        Af32 = part ? kA : qA;
    } else {
        n0 = (sub & 15) * 128;
        int rest = sub >> 4;             // 0..31
        m0 = (rest & 3) * 128;
        bz = rest >> 2;
    }

    // ---- stage ----
#pragma unroll
    for (int it = 0; it < 4; ++it) {
        int chunk = it * 256 + tid;
        int row = chunk >> 3, c8 = chunk & 7;
        if (part < 2) {
            const float* Af = Af32 + (size_t)(m0 + row) * 64 + c8 * 8;
            float4 lo = *(const float4*)Af;
            float4 hi = *(const float4*)(Af + 4);
            uint2 p0 = pack4bf(lo.x, lo.y, lo.z, lo.w);
            uint2 p1 = pack4bf(hi.x, hi.y, hi.z, hi.w);
            *(uint4*)&As[row * 80 + c8 * 8] = uint4{p0.x, p0.y, p1.x, p1.y};
            *(uint4*)&Bs[row * 80 + c8 * 8] =
                *(const uint4*)(WqT + (size_t)(n0 + row) * 64 + c8 * 8);
        } else {
            *(uint4*)&As[row * 80 + c8 * 8] =
                *(const uint4*)(WqT + (size_t)(m0 + row) * 64 + c8 * 8);
            const float* Bf = vA + (size_t)bz * 131072 +
                              (size_t)(n0 + row) * 64 + c8 * 8;
            float4 lo = *(const float4*)Bf;
            float4 hi = *(const float4*)(Bf + 4);
            uint2 p0 = pack4bf(lo.x, lo.y, lo.z, lo.w);
            uint2 p1 = pack4bf(hi.x, hi.y, hi.z, hi.w);
            *(uint4*)&Bs[row * 80 + c8 * 8] = uint4{p0.x, p0.y, p1.x, p1.y};
        }
    }
    __syncthreads();

    floatx4 acc[4][4] = {};
#pragma unroll
    for (int ks = 0; ks < 2; ++ks) {
        short8 af[4], bf[4];
#pragma unroll
        for (int mt = 0; mt < 4; ++mt)
            af[mt] = *(const short8*)&As[(wm * 64 + mt * 16 + c) * 80 + ks * 32 + 8 * Q];
#pragma unroll
        for (int nt = 0; nt < 4; ++nt)
            bf[nt] = *(const short8*)&Bs[(wn * 64 + nt * 16 + c) * 80 + ks * 32 + 8 * Q];
#pragma unroll
        for (int mt = 0; mt < 4; ++mt)
#pragma unroll
            for (int nt = 0; nt < 4; ++nt)
                acc[mt][nt] = __builtin_amdgcn_mfma_f32_16x16x32_bf16(
                    af[mt], bf[nt], acc[mt][nt], 0, 0, 0);
    }
    __syncthreads();   // done reading As/Bs; Cs may overwrite

    // ---- scatter into LDS image (final layout) ----
#pragma unroll
    for (int mt = 0; mt < 4; ++mt)
#pragma unroll
        for (int nt = 0; nt < 4; ++nt) {
            int cl = wn * 64 + nt * 16 + c;        // tile-local col 0..127
#pragma unroll
            for (int r = 0; r < 4; ++r) {
                int rl = wm * 64 + mt * 16 + 4 * Q + r;   // tile-local row
                if (part == 0) {
                    float val = (acc[mt][nt][r] + bq[n0 + cl]) * 0.18033688011f;
                    Cs[rl * 128 + cl] = f2bf(val);
                } else if (part == 1) {
                    float val = acc[mt][nt][r] + bq[n0 + cl];
                    int d = cl & 63, hh = cl >> 6;
                    Cs[rl * 128 + hh * 64 + (((d >> 3) ^ (rl & 7)) * 8) + (d & 7)] =
                        f2bf(val);
                } else {
                    float val = acc[mt][nt][r] + bq[m0 + rl];
                    int d = rl & 63, hl = rl >> 6;
                    int Jl = cl >> 5, kp = cl & 31;
                    int j = 4 * ((kp >> 4) & 1) + (kp & 3);
                    int Qm = (kp >> 2) & 3;
                    int slotm = Qm ^ ((d >> 1) & 3);
                    Cs[(hl * 4 + Jl) * 2048 + d * 32 + slotm * 8 + j] = f2bf(val);
                }
            }
        }
    __syncthreads();

    // ---- coalesced 16B stores: 2048 chunks, 8 passes x 256 threads ----
#pragma unroll
    for (int p = 0; p < 8; ++p) {
        int c2 = p * 256 + tid;                    // 16B chunk id 0..2047
        uint4 vchunk;
        size_t gaddr;
        if (part == 0) {
            int row = c2 >> 4, off16 = c2 & 15;
            vchunk = *(const uint4*)&Cs[row * 128 + off16 * 8];
            gaddr = (size_t)(m0 + row) * HD + n0 + off16 * 8;
            *(uint4*)(qh + gaddr) = vchunk;
        } else if (part == 1) {
            int sp = c2 >> 3, off = c2 & 7;
            int s = sp >> 1, hh = sp & 1;
            vchunk = *(const uint4*)&Cs[s * 128 + hh * 64 + off * 8];
            int grow = m0 + s;
            int b = grow >> 11, sg = grow & 2047;
            int hg = (n0 >> 6) + hh;
            gaddr = ((size_t)(b * 8 + hg)) * 131072 + (size_t)sg * 64 + off * 8;
            *(uint4*)(khS + gaddr) = vchunk;
        } else {
            int region = c2 >> 8, off = c2 & 255;
            int hl = region >> 2, Jl = region & 3;
            vchunk = *(const uint4*)&Cs[region * 2048 + off * 8];
            int hg = (m0 >> 6) + hl;
            int Jg = (n0 >> 5) + Jl;
            gaddr = ((size_t)(bz * 8 + hg)) * 131072 + (size_t)Jg * 2048 + off * 8;
            *(uint4*)(vI + gaddr) = vchunk;
        }
    }
}

// ---------------------------------------------------------------------------
// Generic C = alpha*(A * B^T + bias) — original template (R9), out-GEMM.
// ---------------------------------------------------------------------------
template <int SMODE, bool BIAS_ROW, bool A_F32, bool B_F32>
__global__ __launch_bounds__(256, 2) void gemm_bt(
    const void* __restrict__ A_, int lda, long sA,
    const void* __restrict__ B_, int ldb, long sB,
    void* __restrict__ C, int ldc, long sC,
    const float* __restrict__ bias, int K, float alpha) {
    const int bz = blockIdx.z;
    const int m0 = blockIdx.y * 128, n0 = blockIdx.x * 128;
    __shared__ __align__(16) short As[128 * 80];
    __shared__ __align__(16) short Bs[128 * 80];
    const int tid = threadIdx.x, lane = tid & 63, w = tid >> 6;
    const int c = lane & 15, Q = lane >> 4;
    const int wm = w >> 1, wn = w & 1;
    floatx4 acc[4][4] = {};

    for (int k0 = 0; k0 < K; k0 += 64) {
#pragma unroll
        for (int it = 0; it < 4; ++it) {
            int chunk = it * 256 + tid;
            int row = chunk >> 3, c8 = chunk & 7;
            size_t aoff = (size_t)bz * sA + (size_t)(m0 + row) * lda + k0 + c8 * 8;
            size_t boff = (size_t)bz * sB + (size_t)(n0 + row) * ldb + k0 + c8 * 8;
            if (A_F32) {
                const float* Af = (const float*)A_ + aoff;
                float4 lo = *(const float4*)Af;
                float4 hi = *(const float4*)(Af + 4);
                uint2 p0 = pack4bf(lo.x, lo.y, lo.z, lo.w);
                uint2 p1 = pack4bf(hi.x, hi.y, hi.z, hi.w);
                *(uint4*)&As[row * 80 + c8 * 8] = uint4{p0.x, p0.y, p1.x, p1.y};
            } else {
                *(uint4*)&As[row * 80 + c8 * 8] = *(const uint4*)((const short*)A_ + aoff);
            }
            if (B_F32) {
                const float* Bf = (const float*)B_ + boff;
                float4 lo = *(const float4*)Bf;
                float4 hi = *(const float4*)(Bf + 4);
                uint2 p0 = pack4bf(lo.x, lo.y, lo.z, lo.w);
                uint2 p1 = pack4bf(hi.x, hi.y, hi.z, hi.w);
                *(uint4*)&Bs[row * 80 + c8 * 8] = uint4{p0.x, p0.y, p1.x, p1.y};
            } else {
                *(uint4*)&Bs[row * 80 + c8 * 8] = *(const uint4*)((const short*)B_ + boff);
            }
        }
        __syncthreads();
#pragma unroll
        for (int ks = 0; ks < 2; ++ks) {
            short8 af[4], bf[4];
#pragma unroll
            for (int mt = 0; mt < 4; ++mt)
                af[mt] = *(const short8*)&As[(wm * 64 + mt * 16 + c) * 80 + ks * 32 + 8 * Q];
#pragma unroll
            for (int nt = 0; nt < 4; ++nt)
                bf[nt] = *(const short8*)&Bs[(wn * 64 + nt * 16 + c) * 80 + ks * 32 + 8 * Q];
#pragma unroll
            for (int mt = 0; mt < 4; ++mt)
#pragma unroll
                for (int nt = 0; nt < 4; ++nt)
                    acc[mt][nt] = __builtin_amdgcn_mfma_f32_16x16x32_bf16(
                        af[mt], bf[nt], acc[mt][nt], 0, 0, 0);
        }
        __syncthreads();
    }
#pragma unroll
    for (int mt = 0; mt < 4; ++mt)
#pragma unroll
        for (int nt = 0; nt < 4; ++nt) {
            int col = n0 + wn * 64 + nt * 16 + c;
            float bc = BIAS_ROW ? 0.f : bias[col];
#pragma unroll
            for (int r = 0; r < 4; ++r) {
                int row = m0 + wm * 64 + mt * 16 + 4 * Q + r;
                float val = (acc[mt][nt][r] + (BIAS_ROW ? bias[row] : bc)) * alpha;
                if (SMODE == 0) {
                    ((float*)C)[(size_t)bz * sC + (size_t)row * ldc + col] = val;
                } else if (SMODE == 1) {
                    ((short*)C)[(size_t)bz * sC + (size_t)row * ldc + col] = f2bf(val);
                }
            }
        }
}

// ---------------------------------------------------------------------------
// Flash attention — VERBATIM R5/R9 (passed): KVBLK=64, q-tile 128,
// PV K=32 via vI2, p = 2^z direct, l via ones-column MFMA, ternary masking.
// ---------------------------------------------------------------------------
__global__ __launch_bounds__(512, 4) void fa_kernel(
    const short* __restrict__ qh, const short* __restrict__ khS,
    const short* __restrict__ vI, const unsigned* __restrict__ mbits,
    short* __restrict__ y) {
    const int id = blockIdx.x;          // 0..1023
    const int xcd = id & 7, slot = id >> 3;
    const int qt = slot & 15;           // 128 q-rows each
    const int bh = (slot >> 4) * 8 + xcd;
    const int b = bh >> 3, h = bh & 7;
    const int tid = threadIdx.x, lane = tid & 63, w = tid >> 6;   // w 0..7
    const int c = lane & 15, Q = lane >> 4;
    const int c7 = c & 7;
    const int vslot = Q ^ ((c >> 1) & 3);

    __shared__ __align__(16) short Ks[2 * 4096];   // 2 x 8 KB swizzled K tiles
    __shared__ __align__(16) short Vs[2 * 4096];   // 2 x 8 KB vI2 V tiles

    const short* kbase = khS + (size_t)bh * 131072;
    const short* vbase = vI + (size_t)bh * 131072;
    const int soff = tid * 8;   // shorts; 512 thr x 16B = 8KB = one tile

    // ---- prologue: async-stage tile 0 into buffer 0 ----
    async_copy16(kbase + soff, &Ks[soff]);
    async_copy16(vbase + soff, &Vs[soff]);

    // Q fragments (loop-invariant): q row = qbase0 + c
    const int qbase0 = qt * 128 + w * 16;
    const short* qb = qh + ((size_t)(b * SS + qbase0 + c)) * HD + h * 64;
    short8 qf0 = *(const short8*)(qb + 8 * Q);
    short8 qf1 = *(const short8*)(qb + 32 + 8 * Q);
    const unsigned* mrow = mbits + (size_t)(b * SS + qbase0 + c) * 64;

    // B-frag of all bf16 1.0 (layout-free since every element is identical)
    short8 ones8;
#pragma unroll
    for (int i = 0; i < 8; ++i) ones8[i] = (short)0x3F80;

    floatx4 o[4] = {};
    floatx4 acc_l = {};

    __syncthreads();   // drains prologue stage for all waves

    for (int kt2 = 0; kt2 < 16; ++kt2) {
        uint4 mr4 = *(const uint4*)(mrow + kt2 * 4);
#pragma unroll
        for (int hf = 0; hf < 2; ++hf) {
            const int kt = 2 * kt2 + hf;
            const int cb = hf * 4096;          // compile-time buffer bases
            const int nb = (1 - hf) * 4096;
            const unsigned mlo = hf ? mr4.z : mr4.x;
            const unsigned mhi = hf ? mr4.w : mr4.y;

            // ---- issue async stage of tile kt+1 into the other buffer ----
            if (kt < 31) {
                const short* kg = kbase + (kt + 1) * 4096;
                const short* vg = vbase + (kt + 1) * 4096;
                async_copy16(kg + soff, &Ks[nb + soff]);
                async_copy16(vg + soff, &Vs[nb + soff]);
            }

            // ---- scores -> P = 2^z (masked -> 0), packed bf16 ----
            short4v p4[4];
#pragma unroll
            for (int jt = 0; jt < 4; ++jt) {
                short8 k0 = *(const short8*)&Ks[cb + (16 * jt + c) * 64 + (Q ^ c7) * 8];
                short8 k1 = *(const short8*)&Ks[cb + (16 * jt + c) * 64 + ((Q + 4) ^ c7) * 8];
                floatx4 z = {};
                z = __builtin_amdgcn_mfma_f32_16x16x32_bf16(k0, qf0, z, 0, 0, 0);
                z = __builtin_amdgcn_mfma_f32_16x16x32_bf16(k1, qf1, z, 0, 0, 0);
                unsigned mwd = (jt & 2) ? mhi : mlo;
                unsigned nib = (mwd >> (((jt & 1) << 4) + 4 * Q)) & 0xFu;
                float p0 = (nib & 1u) ? 0.f : __builtin_amdgcn_exp2f(z[0]);
                float p1 = (nib & 2u) ? 0.f : __builtin_amdgcn_exp2f(z[1]);
                float p2 = (nib & 4u) ? 0.f : __builtin_amdgcn_exp2f(z[2]);
                float p3 = (nib & 8u) ? 0.f : __builtin_amdgcn_exp2f(z[3]);
                p4[jt] = pack4bf_s4(p0, p1, p2, p3);
            }

            // ---- PV (16x16x32) + l via ones-column MFMA ----
#pragma unroll
            for (int J = 0; J < 2; ++J) {
                short8 v8 = __builtin_shufflevector(p4[2 * J], p4[2 * J + 1],
                                                    0, 1, 2, 3, 4, 5, 6, 7);
                acc_l = __builtin_amdgcn_mfma_f32_16x16x32_bf16(v8, ones8, acc_l, 0, 0, 0);
#pragma unroll
                for (int nt = 0; nt < 4; ++nt) {
                    short8 vf = *(const short8*)&Vs[cb + J * 2048 + (16 * nt + c) * 32 + vslot * 8];
                    o[nt] = __builtin_amdgcn_mfma_f32_16x16x32_bf16(v8, vf, o[nt], 0, 0, 0);
                }
            }
            if (kt < 31) __syncthreads();
        }
    }

    // ---- epilogue: O/l -> y bf16 (acc_l[r] = l of row 4Q+r; no shuffle) ----
#pragma unroll
    for (int r = 0; r < 4; ++r) {
        float inv = 1.0f / acc_l[r];
        int row = qbase0 + 4 * Q + r;
#pragma unroll
        for (int nt = 0; nt < 4; ++nt)
            y[((size_t)(b * SS + row)) * HD + h * 64 + 16 * nt + c] =
                f2bf(o[nt][r] * inv);
    }
}

// ---------------------------------------------------------------------------
extern "C" void kernel_launch(void* const* d_in, const int* in_sizes, int n_in,
                              void* d_out, int out_size, void* d_ws, size_t ws_size,
                              hipStream_t stream) {
    const float* q    = (const float*)d_in[0];
    const float* k    = (const float*)d_in[1];
    const float* v    = (const float*)d_in[2];
    const float* mask = (const float*)d_in[3];
    const float* Wq   = (const float*)d_in[4];
    const float* bq   = (const float*)d_in[5];
    const float* Wo   = (const float*)d_in[6];
    const float* bo   = (const float*)d_in[7];

    char* ws = (char*)d_ws;
    const size_t MB = 1ull << 20;
    short* WqT = (short*)(ws + 0 * MB);    // 64 KB
    short* WoT = (short*)(ws + 1 * MB);    // 512 KB
    short* qh  = (short*)(ws + 8 * MB);    // 16 MB  [b][s][hd], pre-scaled log2e/8
    short* khS = (short*)(ws + 24 * MB);   // 16 MB  swizzled [bh][s][dg^s&7][8]
    short* vI  = (short*)(ws + 40 * MB);   // 16 MB  vI2 PV-K32 layout
    unsigned long long* bits = (unsigned long long*)(ws + 56 * MB);  // 4 MB
    short* yb  = (short*)(ws + 60 * MB);   // 16 MB  [b][s][hd]
    float* out = (float*)d_out;

    // 1) tiny: WqT transpose (proj dependency)
    wqt_prep_kernel<<<128, 256, 0, stream>>>(Wq, WqT);
    // 2) fused aux: mask bits + WoT + q/k/v projection in ONE dispatch
    fused_aux_kernel<<<18944, 256, 0, stream>>>(
        mask, bits, Wo, WoT, q, k, v, WqT, bq, qh, khS, vI);
    // 3) attention (verbatim R5/R9)
    fa_kernel<<<dim3(1024, 1, 1), 512, 0, stream>>>(qh, khS, vI, (const unsigned*)bits, yb);
    // 4) out = y @ Wo + bo (fp32, R9 template)
    gemm_bt<0, false, false, false><<<dim3(4, 128, 1), 256, 0, stream>>>(
        yb, 512, 0, WoT, 512, 0, (void*)out, 512, 0, bo, 512, 1.0f);
}

// Round 14
// 349.517 us; speedup vs baseline: 1.1860x; 1.1860x over previous
//
#include <hip/hip_runtime.h>
#include <hip/hip_bf16.h>

// Problem constants
#define BB 8
#define SS 2048
#define HD 512   // H*DK
#define DM 512

typedef __attribute__((ext_vector_type(8))) short short8;   // 8 bf16
typedef __attribute__((ext_vector_type(4))) short short4v;  // 4 bf16
typedef __attribute__((ext_vector_type(4))) float floatx4;  // MFMA C/D

// HW packed f32->bf16 (RNE): gfx950 v_cvt_pk_bf16_f32, low half = a.
__device__ __forceinline__ unsigned cvt_pk_bf16(float a, float b) {
    unsigned r;
    asm("v_cvt_pk_bf16_f32 %0, %1, %2" : "=v"(r) : "v"(a), "v"(b));
    return r;
}

__device__ __forceinline__ short f2bf(float f) {
    return (short)(cvt_pk_bf16(f, f) & 0xFFFFu);
}

__device__ __forceinline__ uint2 pack4bf(float a, float b, float cc, float d) {
    return uint2{cvt_pk_bf16(a, b), cvt_pk_bf16(cc, d)};
}

__device__ __forceinline__ short4v pack4bf_s4(float a, float b, float cc, float d) {
    uint2 u = pack4bf(a, b, cc, d);
    short4v s;
    __builtin_memcpy(&s, &u, 8);
    return s;
}

// async global->LDS, 16B per lane. Dest MUST be wave-uniform base + lane*16.
__device__ __forceinline__ void async_copy16(const short* g, short* l) {
    __builtin_amdgcn_global_load_lds(
        (const __attribute__((address_space(1))) void*)g,
        (__attribute__((address_space(3))) void*)l, 16, 0, 0);
}

// ---------------------------------------------------------------------------
// prep: build WqT[512][64], WoT[512][512] (bf16, transposed)   [R5 verbatim]
// ---------------------------------------------------------------------------
__global__ void prep_kernel(const float* __restrict__ Wq, const float* __restrict__ Wo,
                            short* __restrict__ WqT, short* __restrict__ WoT) {
    int idx = blockIdx.x * 256 + threadIdx.x;             // 0 .. 262143
    if (idx < HD * 64) {                                  // 32768
        int o = idx >> 6, i = idx & 63;
        WqT[idx] = f2bf(Wq[i * HD + o]);
    }
    {
        int o = idx >> 9, i = idx & 511;
        WoT[idx] = f2bf(Wo[i * DM + o]);
    }
}

// ---------------------------------------------------------------------------
// maskbits: bit=1 where mask==1.0 (those get zeroed P).       [R5 verbatim]
// ---------------------------------------------------------------------------
__global__ void maskbits_kernel(const float* __restrict__ mask,
                                unsigned long long* __restrict__ bits) {
    int gw = blockIdx.x * 4 + (threadIdx.x >> 6);   // global wave id
    int lane = threadIdx.x & 63;
    size_t base = (size_t)gw * 256;
    float4 v = *(const float4*)(mask + base + (size_t)lane * 4);
    unsigned long long nib =
        (v.x == 1.0f ? 1ull : 0ull) | (v.y == 1.0f ? 2ull : 0ull) |
        (v.z == 1.0f ? 4ull : 0ull) | (v.w == 1.0f ? 8ull : 0ull);
    unsigned long long word = nib << (4 * (lane & 15));
    word |= __shfl_xor(word, 1);
    word |= __shfl_xor(word, 2);
    word |= __shfl_xor(word, 4);
    word |= __shfl_xor(word, 8);
    if ((lane & 15) == 0) bits[gw * 4 + (lane >> 4)] = word;
}

// ---------------------------------------------------------------------------
// Generic C = alpha*(A * B^T + bias).  A:[M][K] row-major, Bt:[N][K] row-major.
// SMODE: 0 = fp32 natural, 1 = bf16 natural, 2 = K-swizzled (khS),
//        3 = V PV-K32 layout (vI2)                            [R5 verbatim]
// ---------------------------------------------------------------------------
template <int SMODE, bool BIAS_ROW, bool A_F32, bool B_F32>
__global__ __launch_bounds__(256, 2) void gemm_bt(
    const void* __restrict__ A_, int lda, long sA,
    const void* __restrict__ B_, int ldb, long sB,
    void* __restrict__ C, int ldc, long sC,
    const float* __restrict__ bias, int K, float alpha) {
    const int bz = blockIdx.z;
    const int m0 = blockIdx.y * 128, n0 = blockIdx.x * 128;
    __shared__ __align__(16) short As[128 * 80];
    __shared__ __align__(16) short Bs[128 * 80];
    const int tid = threadIdx.x, lane = tid & 63, w = tid >> 6;
    const int c = lane & 15, Q = lane >> 4;
    const int wm = w >> 1, wn = w & 1;
    floatx4 acc[4][4] = {};

    for (int k0 = 0; k0 < K; k0 += 64) {
#pragma unroll
        for (int it = 0; it < 4; ++it) {
            int chunk = it * 256 + tid;
            int row = chunk >> 3, c8 = chunk & 7;
            size_t aoff = (size_t)bz * sA + (size_t)(m0 + row) * lda + k0 + c8 * 8;
            size_t boff = (size_t)bz * sB + (size_t)(n0 + row) * ldb + k0 + c8 * 8;
            if (A_F32) {
                const float* Af = (const float*)A_ + aoff;
                float4 lo = *(const float4*)Af;
                float4 hi = *(const float4*)(Af + 4);
                uint2 p0 = pack4bf(lo.x, lo.y, lo.z, lo.w);
                uint2 p1 = pack4bf(hi.x, hi.y, hi.z, hi.w);
                *(uint4*)&As[row * 80 + c8 * 8] = uint4{p0.x, p0.y, p1.x, p1.y};
            } else {
                *(uint4*)&As[row * 80 + c8 * 8] = *(const uint4*)((const short*)A_ + aoff);
            }
            if (B_F32) {
                const float* Bf = (const float*)B_ + boff;
                float4 lo = *(const float4*)Bf;
                float4 hi = *(const float4*)(Bf + 4);
                uint2 p0 = pack4bf(lo.x, lo.y, lo.z, lo.w);
                uint2 p1 = pack4bf(hi.x, hi.y, hi.z, hi.w);
                *(uint4*)&Bs[row * 80 + c8 * 8] = uint4{p0.x, p0.y, p1.x, p1.y};
            } else {
                *(uint4*)&Bs[row * 80 + c8 * 8] = *(const uint4*)((const short*)B_ + boff);
            }
        }
        __syncthreads();
#pragma unroll
        for (int ks = 0; ks < 2; ++ks) {
            short8 af[4], bf[4];
#pragma unroll
            for (int mt = 0; mt < 4; ++mt)
                af[mt] = *(const short8*)&As[(wm * 64 + mt * 16 + c) * 80 + ks * 32 + 8 * Q];
#pragma unroll
            for (int nt = 0; nt < 4; ++nt)
                bf[nt] = *(const short8*)&Bs[(wn * 64 + nt * 16 + c) * 80 + ks * 32 + 8 * Q];
#pragma unroll
            for (int mt = 0; mt < 4; ++mt)
#pragma unroll
                for (int nt = 0; nt < 4; ++nt)
                    acc[mt][nt] = __builtin_amdgcn_mfma_f32_16x16x32_bf16(
                        af[mt], bf[nt], acc[mt][nt], 0, 0, 0);
        }
        __syncthreads();
    }
#pragma unroll
    for (int mt = 0; mt < 4; ++mt)
#pragma unroll
        for (int nt = 0; nt < 4; ++nt) {
            int col = n0 + wn * 64 + nt * 16 + c;
            float bc = BIAS_ROW ? 0.f : bias[col];
#pragma unroll
            for (int r = 0; r < 4; ++r) {
                int row = m0 + wm * 64 + mt * 16 + 4 * Q + r;
                float val = (acc[mt][nt][r] + (BIAS_ROW ? bias[row] : bc)) * alpha;
                if (SMODE == 0) {
                    ((float*)C)[(size_t)bz * sC + (size_t)row * ldc + col] = val;
                } else if (SMODE == 1) {
                    ((short*)C)[(size_t)bz * sC + (size_t)row * ldc + col] = f2bf(val);
                } else if (SMODE == 2) {
                    // row = b*2048 + s (M=16384), col = hd
                    int b = row >> 11, s = row & 2047, h = col >> 6, d = col & 63;
                    size_t idx = ((size_t)(b * 8 + h)) * 131072 + (size_t)s * 64 +
                                 (size_t)(((d >> 3) ^ (s & 7)) * 8 + (d & 7));
                    ((short*)C)[idx] = f2bf(val);
                } else {
                    // row = hd (M=512), col = s = logical k (N=2048), b = bz
                    int h = row >> 6, d = row & 63, s = col;
                    int J = s >> 5;
                    int j = 4 * ((s >> 4) & 1) + (s & 3);
                    int Qm = (s >> 2) & 3;
                    int slotm = Qm ^ ((d >> 1) & 3);
                    size_t idx = ((size_t)(bz * 8 + h)) * 131072 + (size_t)J * 2048 +
                                 (size_t)(d * 32 + slotm * 8 + j);
                    ((short*)C)[idx] = f2bf(val);
                }
            }
        }
}

// ---------------------------------------------------------------------------
// Flash attention R14 = R5 fa (ternary masking, passed 3x) + s_setprio(1)
// around the MFMA clusters (T5, +4-7% on attn per m191). Pure scheduling
// hint: cannot change results. LUT permanently abandoned (failed 2x).
// ---------------------------------------------------------------------------
__global__ __launch_bounds__(512, 4) void fa_kernel(
    const short* __restrict__ qh, const short* __restrict__ khS,
    const short* __restrict__ vI, const unsigned* __restrict__ mbits,
    short* __restrict__ y) {
    const int id = blockIdx.x;          // 0..1023
    const int xcd = id & 7, slot = id >> 3;
    const int qt = slot & 15;           // 128 q-rows each
    const int bh = (slot >> 4) * 8 + xcd;
    const int b = bh >> 3, h = bh & 7;
    const int tid = threadIdx.x, lane = tid & 63, w = tid >> 6;   // w 0..7
    const int c = lane & 15, Q = lane >> 4;
    const int c7 = c & 7;
    const int vslot = Q ^ ((c >> 1) & 3);

    __shared__ __align__(16) short Ks[2 * 4096];   // 2 x 8 KB swizzled K tiles
    __shared__ __align__(16) short Vs[2 * 4096];   // 2 x 8 KB vI2 V tiles

    const short* kbase = khS + (size_t)bh * 131072;
    const short* vbase = vI + (size_t)bh * 131072;
    const int soff = tid * 8;   // shorts; 512 thr x 16B = 8KB = one tile

    // ---- prologue: async-stage tile 0 into buffer 0 ----
    async_copy16(kbase + soff, &Ks[soff]);
    async_copy16(vbase + soff, &Vs[soff]);

    // Q fragments (loop-invariant): q row = qbase0 + c
    const int qbase0 = qt * 128 + w * 16;
    const short* qb = qh + ((size_t)(b * SS + qbase0 + c)) * HD + h * 64;
    short8 qf0 = *(const short8*)(qb + 8 * Q);
    short8 qf1 = *(const short8*)(qb + 32 + 8 * Q);
    const unsigned* mrow = mbits + (size_t)(b * SS + qbase0 + c) * 64;

    // B-frag of all bf16 1.0 (layout-free since every element is identical)
    short8 ones8;
#pragma unroll
    for (int i = 0; i < 8; ++i) ones8[i] = (short)0x3F80;

    floatx4 o[4] = {};
    floatx4 acc_l = {};

    __syncthreads();   // drains prologue stage for all waves

    for (int kt2 = 0; kt2 < 16; ++kt2) {
        uint4 mr4 = *(const uint4*)(mrow + kt2 * 4);
#pragma unroll
        for (int hf = 0; hf < 2; ++hf) {
            const int kt = 2 * kt2 + hf;
            const int cb = hf * 4096;          // compile-time buffer bases
            const int nb = (1 - hf) * 4096;
            const unsigned mlo = hf ? mr4.z : mr4.x;
            const unsigned mhi = hf ? mr4.w : mr4.y;

            // ---- issue async stage of tile kt+1 into the other buffer ----
            if (kt < 31) {
                const short* kg = kbase + (kt + 1) * 4096;
                const short* vg = vbase + (kt + 1) * 4096;
                async_copy16(kg + soff, &Ks[nb + soff]);
                async_copy16(vg + soff, &Vs[nb + soff]);
            }

            // ---- scores -> P = 2^z (masked -> 0), packed bf16 ----
            short4v p4[4];
#pragma unroll
            for (int jt = 0; jt < 4; ++jt) {
                short8 k0 = *(const short8*)&Ks[cb + (16 * jt + c) * 64 + (Q ^ c7) * 8];
                short8 k1 = *(const short8*)&Ks[cb + (16 * jt + c) * 64 + ((Q + 4) ^ c7) * 8];
                floatx4 z = {};
                __builtin_amdgcn_s_setprio(1);
                z = __builtin_amdgcn_mfma_f32_16x16x32_bf16(k0, qf0, z, 0, 0, 0);
                z = __builtin_amdgcn_mfma_f32_16x16x32_bf16(k1, qf1, z, 0, 0, 0);
                __builtin_amdgcn_s_setprio(0);
                unsigned mwd = (jt & 2) ? mhi : mlo;
                unsigned nib = (mwd >> (((jt & 1) << 4) + 4 * Q)) & 0xFu;
                float p0 = (nib & 1u) ? 0.f : __builtin_amdgcn_exp2f(z[0]);
                float p1 = (nib & 2u) ? 0.f : __builtin_amdgcn_exp2f(z[1]);
                float p2 = (nib & 4u) ? 0.f : __builtin_amdgcn_exp2f(z[2]);
                float p3 = (nib & 8u) ? 0.f : __builtin_amdgcn_exp2f(z[3]);
                p4[jt] = pack4bf_s4(p0, p1, p2, p3);
            }

            // ---- PV (16x16x32) + l via ones-column MFMA ----
            __builtin_amdgcn_s_setprio(1);
#pragma unroll
            for (int J = 0; J < 2; ++J) {
                short8 v8 = __builtin_shufflevector(p4[2 * J], p4[2 * J + 1],
                                                    0, 1, 2, 3, 4, 5, 6, 7);
                acc_l = __builtin_amdgcn_mfma_f32_16x16x32_bf16(v8, ones8, acc_l, 0, 0, 0);
#pragma unroll
                for (int nt = 0; nt < 4; ++nt) {
                    short8 vf = *(const short8*)&Vs[cb + J * 2048 + (16 * nt + c) * 32 + vslot * 8];
                    o[nt] = __builtin_amdgcn_mfma_f32_16x16x32_bf16(v8, vf, o[nt], 0, 0, 0);
                }
            }
            __builtin_amdgcn_s_setprio(0);
            if (kt < 31) __syncthreads();
        }
    }

    // ---- epilogue: O/l -> y bf16 (acc_l[r] = l of row 4Q+r; no shuffle) ----
#pragma unroll
    for (int r = 0; r < 4; ++r) {
        float inv = 1.0f / acc_l[r];
        int row = qbase0 + 4 * Q + r;
#pragma unroll
        for (int nt = 0; nt < 4; ++nt)
            y[((size_t)(b * SS + row)) * HD + h * 64 + 16 * nt + c] =
                f2bf(o[nt][r] * inv);
    }
}

// ---------------------------------------------------------------------------
extern "C" void kernel_launch(void* const* d_in, const int* in_sizes, int n_in,
                              void* d_out, int out_size, void* d_ws, size_t ws_size,
                              hipStream_t stream) {
    const float* q    = (const float*)d_in[0];
    const float* k    = (const float*)d_in[1];
    const float* v    = (const float*)d_in[2];
    const float* mask = (const float*)d_in[3];
    const float* Wq   = (const float*)d_in[4];
    const float* bq   = (const float*)d_in[5];
    const float* Wo   = (const float*)d_in[6];
    const float* bo   = (const float*)d_in[7];

    char* ws = (char*)d_ws;
    const size_t MB = 1ull << 20;
    short* WqT = (short*)(ws + 0 * MB);    // 64 KB
    short* WoT = (short*)(ws + 1 * MB);    // 512 KB
    short* qh  = (short*)(ws + 8 * MB);    // 16 MB  [b][s][hd], pre-scaled log2e/8
    short* khS = (short*)(ws + 24 * MB);   // 16 MB  swizzled [bh][s][dg^s&7][8]
    short* vI  = (short*)(ws + 40 * MB);   // 16 MB  vI2 PV-K32 layout
    unsigned long long* bits = (unsigned long long*)(ws + 56 * MB);  // 4 MB
    short* yb  = (short*)(ws + 60 * MB);   // 16 MB  [b][s][hd]
    float* out = (float*)d_out;

    const float ALPHA_Q = 0.18033688011f;  // log2(e)/8

    prep_kernel<<<1024, 256, 0, stream>>>(Wq, Wo, WqT, WoT);
    maskbits_kernel<<<32768, 256, 0, stream>>>(mask, bits);

    // qh = (q @ Wq + bq) * alpha   (natural layout)
    gemm_bt<1, false, true, false><<<dim3(4, 128, 1), 256, 0, stream>>>(
        q, 64, 0, WqT, 64, 0, (void*)qh, 512, 0, bq, 64, ALPHA_Q);
    // khS = swizzled(k @ Wq + bq)
    gemm_bt<2, false, true, false><<<dim3(4, 128, 1), 256, 0, stream>>>(
        k, 64, 0, WqT, 64, 0, (void*)khS, 0, 0, bq, 64, 1.0f);
    // vI2 = PV-K32 layout of (WqT @ v^T + bq), batched over b
    gemm_bt<3, true, false, true><<<dim3(16, 4, BB), 256, 0, stream>>>(
        WqT, 64, 0, v, 64, (long)SS * 64, (void*)vI, 0, 0, bq, 64, 1.0f);

    fa_kernel<<<dim3(1024, 1, 1), 512, 0, stream>>>(qh, khS, vI, (const unsigned*)bits, yb);

    // out = y @ Wo + bo  (fp32)
    gemm_bt<0, false, false, false><<<dim3(4, 128, 1), 256, 0, stream>>>(
        yb, 512, 0, WoT, 512, 0, (void*)out, 512, 0, bo, 512, 1.0f);
}